// Round 1
// baseline (303.333 us; speedup 1.0000x reference)
//
#include <hip/hip_runtime.h>

// Problem constants (reference: Q=2048, N=32768, D=512, C=100)
#define QN 2048
#define NN 32768
#define DD 512
#define CC 100
#define MAXTILES 356            // sum ceil(n_c/128) <= 256 + 100
#define MAXNP (MAXTILES * 128)  // 45568 max padded columns

typedef float f32x4 __attribute__((ext_vector_type(4)));
typedef __bf16 bf16x8 __attribute__((ext_vector_type(8)));
typedef unsigned short u16x8 __attribute__((ext_vector_type(8)));

// meta layout (int32 indices within first 4 KiB of ws)
#define M_HIST 0    // [100] class histogram
#define M_FILL 128  // [100] scatter fill counters
#define M_SEG 256   // [101] padded start column per class
#define M_TC 384    // [356] class of each 128-col tile
#define M_NT 768    // number of 128-col tiles
#define M_NCOL 769  // total padded columns

// ws byte offsets
#define OFF_X2 4096
#define OFF_DB2 16384
#define OFF_MIN 262144
#define OFF_XB (1u << 21)
#define OFF_DBS (1u << 22)

__device__ __forceinline__ unsigned short f2bf(float f) {
  unsigned u = __float_as_uint(f);
  unsigned r = 0x7FFFu + ((u >> 16) & 1u);  // round-to-nearest-even
  return (unsigned short)((u + r) >> 16);
}

typedef const __attribute__((address_space(1))) void* gptr_t;
typedef __attribute__((address_space(3))) void* lptr_t;
__device__ __forceinline__ void gload_lds16(const void* g, void* l) {
  __builtin_amdgcn_global_load_lds((gptr_t)g, (lptr_t)l, 16, 0, 0);
}

// ---- class histogram (LDS-local then one flush per block) ----
__global__ void k_hist(const int* __restrict__ labels, int* __restrict__ meta) {
  __shared__ int h[CC];
  int t = threadIdx.x;
  if (t < CC) h[t] = 0;
  __syncthreads();
#pragma unroll
  for (int i = 0; i < 4; ++i) {
    int n = blockIdx.x * 1024 + i * 256 + t;
    atomicAdd(&h[labels[n]], 1);
  }
  __syncthreads();
  if (t < CC) atomicAdd(&meta[M_HIST + t], h[t]);
}

// ---- serial scan over 100 classes: segment starts, tile->class, NT ----
__global__ void k_scan(int* __restrict__ meta) {
  if (threadIdx.x == 0) {
    int col = 0, t = 0;
    for (int c = 0; c < CC; ++c) {
      meta[M_SEG + c] = col;
      int tiles = (meta[M_HIST + c] + 127) >> 7;
      for (int i = 0; i < tiles; ++i) meta[M_TC + t++] = c;
      col += tiles << 7;
    }
    meta[M_SEG + CC] = col;
    meta[M_NT] = t;
    meta[M_NCOL] = col;
  }
}

// ---- x: fp32 -> bf16 + row sumsq. One wave per row. ----
__global__ void k_prep_x(const float* __restrict__ x, unsigned short* __restrict__ xb,
                         float* __restrict__ x2) {
  int w = threadIdx.x >> 6, lane = threadIdx.x & 63;
  int q = blockIdx.x * 4 + w;
  const float4* row = (const float4*)(x + (size_t)q * DD);
  float4 v0 = row[lane * 2];
  float4 v1 = row[lane * 2 + 1];
  float s = v0.x * v0.x + v0.y * v0.y + v0.z * v0.z + v0.w * v0.w +
            v1.x * v1.x + v1.y * v1.y + v1.z * v1.z + v1.w * v1.w;
  u16x8 o;
  o[0] = f2bf(v0.x); o[1] = f2bf(v0.y); o[2] = f2bf(v0.z); o[3] = f2bf(v0.w);
  o[4] = f2bf(v1.x); o[5] = f2bf(v1.y); o[6] = f2bf(v1.z); o[7] = f2bf(v1.w);
  ((u16x8*)(xb + (size_t)q * DD))[lane] = o;
#pragma unroll
  for (int m = 32; m; m >>= 1) s += __shfl_xor(s, m);
  if (lane == 0) x2[q] = s;
}

// ---- db: scatter row n -> sorted padded position, fp32 -> bf16, sumsq ----
__global__ void k_scatter(const float* __restrict__ db, const int* __restrict__ labels,
                          int* __restrict__ meta, unsigned short* __restrict__ dbs,
                          float* __restrict__ db2s) {
  int w = threadIdx.x >> 6, lane = threadIdx.x & 63;
  int n = blockIdx.x * 4 + w;
  int c = labels[n];
  int pos = 0;
  if (lane == 0) pos = meta[M_SEG + c] + atomicAdd(&meta[M_FILL + c], 1);
  pos = __shfl(pos, 0);
  const float4* row = (const float4*)(db + (size_t)n * DD);
  float4 v0 = row[lane * 2];
  float4 v1 = row[lane * 2 + 1];
  float s = v0.x * v0.x + v0.y * v0.y + v0.z * v0.z + v0.w * v0.w +
            v1.x * v1.x + v1.y * v1.y + v1.z * v1.z + v1.w * v1.w;
  u16x8 o;
  o[0] = f2bf(v0.x); o[1] = f2bf(v0.y); o[2] = f2bf(v0.z); o[3] = f2bf(v0.w);
  o[4] = f2bf(v1.x); o[5] = f2bf(v1.y); o[6] = f2bf(v1.z); o[7] = f2bf(v1.w);
  ((u16x8*)(dbs + (size_t)pos * DD))[lane] = o;
#pragma unroll
  for (int m = 32; m; m >>= 1) s += __shfl_xor(s, m);
  if (lane == 0) db2s[pos] = s;
}

// ---- fill padded slots: zero rows, db2 = +inf (never wins the min) ----
__global__ void k_pad(const int* __restrict__ meta, unsigned short* __restrict__ dbs,
                      float* __restrict__ db2s) {
  int w = threadIdx.x >> 6, lane = threadIdx.x & 63;
  int p = blockIdx.x * 4 + w;
  if (p >= meta[M_NCOL]) return;
  int c = meta[M_TC + (p >> 7)];
  if (p - meta[M_SEG + c] < meta[M_HIST + c]) return;  // real row, written by scatter
  u16x8 z = {0, 0, 0, 0, 0, 0, 0, 0};
  ((u16x8*)(dbs + (size_t)p * DD))[lane] = z;
  if (lane == 0) db2s[p] = __builtin_inff();
}

__global__ void k_initmin(unsigned* __restrict__ mb) {
  int i = blockIdx.x * 256 + threadIdx.x;
  if (i < QN * CC) mb[i] = 0x7F800000u;  // +inf bits
}

// ---- fused bf16 MFMA GEMM (128x128 tile, BK=32) + per-class row-min ----
__launch_bounds__(256)
__global__ void k_gemm(const unsigned short* __restrict__ xb,
                       const unsigned short* __restrict__ dbs,
                       const float* __restrict__ x2, const float* __restrict__ db2s,
                       const int* __restrict__ meta, unsigned* __restrict__ minbits) {
  int tq = blockIdx.x, tn = blockIdx.y;
  if (tn >= meta[M_NT]) return;
  int cls = meta[M_TC + tn];

  __shared__ __align__(16) unsigned short As[128 * 32];
  __shared__ __align__(16) unsigned short Bs[128 * 32];

  int t = threadIdx.x;
  int lane = t & 63;
  int wid = t >> 6;
  int wm = wid >> 1, wn = wid & 1;  // 2x2 waves of 64x64

  f32x4 acc[4][4];
#pragma unroll
  for (int m = 0; m < 4; ++m)
#pragma unroll
    for (int n = 0; n < 4; ++n) acc[m][n] = (f32x4){0.f, 0.f, 0.f, 0.f};

  // staging: thread t loads 16B for row j*64 + t/4, col (t&3)*8 (x2 chunks j=0,1)
  const unsigned short* Abase = xb + (size_t)tq * 128 * DD + (size_t)(t >> 2) * DD + (t & 3) * 8;
  const unsigned short* Bbase = dbs + (size_t)tn * 128 * DD + (size_t)(t >> 2) * DD + (t & 3) * 8;

  for (int kt = 0; kt < DD / 32; ++kt) {
    int k0 = kt * 32;
#pragma unroll
    for (int j = 0; j < 2; ++j) {
      gload_lds16(Abase + (size_t)j * 64 * DD + k0, As + j * 2048 + t * 8);
      gload_lds16(Bbase + (size_t)j * 64 * DD + k0, Bs + j * 2048 + t * 8);
    }
    asm volatile("s_waitcnt vmcnt(0)" ::: "memory");
    __syncthreads();

    bf16x8 af[4], bfb[4];
#pragma unroll
    for (int m = 0; m < 4; ++m)
      af[m] = *(const bf16x8*)(As + (wm * 64 + m * 16 + (lane & 15)) * 32 + (lane >> 4) * 8);
#pragma unroll
    for (int n = 0; n < 4; ++n)
      bfb[n] = *(const bf16x8*)(Bs + (wn * 64 + n * 16 + (lane & 15)) * 32 + (lane >> 4) * 8);
#pragma unroll
    for (int m = 0; m < 4; ++m)
#pragma unroll
      for (int n = 0; n < 4; ++n)
        acc[m][n] = __builtin_amdgcn_mfma_f32_16x16x32_bf16(af[m], bfb[n], acc[m][n], 0, 0, 0);
    __syncthreads();
  }

  // Epilogue: whole block is one class. d2 = x2[q] + min_n(db2[n] - 2*dot).
  int g = lane >> 4;
  int cl = lane & 15;
  float db2v[4];
#pragma unroll
  for (int n = 0; n < 4; ++n) db2v[n] = db2s[tn * 128 + wn * 64 + n * 16 + cl];

#pragma unroll
  for (int m = 0; m < 4; ++m) {
    int rowb = tq * 128 + wm * 64 + m * 16 + g * 4;
#pragma unroll
    for (int r = 0; r < 4; ++r) {
      float v = db2v[0] - 2.0f * acc[m][0][r];
      v = fminf(v, db2v[1] - 2.0f * acc[m][1][r]);
      v = fminf(v, db2v[2] - 2.0f * acc[m][2][r]);
      v = fminf(v, db2v[3] - 2.0f * acc[m][3][r]);
#pragma unroll
      for (int s = 1; s < 16; s <<= 1) v = fminf(v, __shfl_xor(v, s));
      if (cl == 0) {
        float d = sqrtf(fmaxf(x2[rowb + r] + v, 0.0f));
        atomicMin(minbits + (size_t)(rowb + r) * CC + cls, __float_as_uint(d));
      }
    }
  }
}

__global__ void k_final(const unsigned* __restrict__ mb, float* __restrict__ out) {
  int i = blockIdx.x * 256 + threadIdx.x;
  if (i < QN * CC) out[i] = -__uint_as_float(mb[i]);
}

extern "C" void kernel_launch(void* const* d_in, const int* in_sizes, int n_in,
                              void* d_out, int out_size, void* d_ws, size_t ws_size,
                              hipStream_t stream) {
  (void)in_sizes; (void)n_in; (void)out_size; (void)ws_size;
  const float* x = (const float*)d_in[0];
  const float* db = (const float*)d_in[1];
  const int* labels = (const int*)d_in[2];

  char* ws = (char*)d_ws;
  int* meta = (int*)ws;
  float* x2 = (float*)(ws + OFF_X2);
  float* db2s = (float*)(ws + OFF_DB2);
  unsigned* minbits = (unsigned*)(ws + OFF_MIN);
  unsigned short* xb = (unsigned short*)(ws + OFF_XB);
  unsigned short* dbs = (unsigned short*)(ws + OFF_DBS);

  hipMemsetAsync(ws, 0, 4096, stream);
  k_hist<<<NN / 1024, 256, 0, stream>>>(labels, meta);
  k_scan<<<1, 64, 0, stream>>>(meta);
  k_prep_x<<<QN / 4, 256, 0, stream>>>(x, xb, x2);
  k_scatter<<<NN / 4, 256, 0, stream>>>(db, labels, meta, dbs, db2s);
  k_pad<<<MAXNP / 4, 256, 0, stream>>>(meta, dbs, db2s);
  k_initmin<<<(QN * CC + 255) / 256, 256, 0, stream>>>(minbits);
  k_gemm<<<dim3(16, MAXTILES), 256, 0, stream>>>(xb, dbs, x2, db2s, meta, minbits);
  k_final<<<(QN * CC + 255) / 256, 256, 0, stream>>>(minbits, (float*)d_out);
}

// Round 2
// 302.635 us; speedup vs baseline: 1.0023x; 1.0023x over previous
//
#include <hip/hip_runtime.h>

// Problem constants (reference: Q=2048, N=32768, D=512, C=100)
#define QN 2048
#define NN 32768
#define DD 512
#define CC 100
#define MAXTILES 356            // sum ceil(n_c/128) <= 256 + 100
#define MAXNP (MAXTILES * 128)  // 45568 max padded columns

typedef float f32x4 __attribute__((ext_vector_type(4)));
typedef __bf16 bf16x8 __attribute__((ext_vector_type(8)));
typedef unsigned short u16x8 __attribute__((ext_vector_type(8)));

// meta layout (int32 indices within first 4 KiB of ws)
#define M_HIST 0    // [100] class histogram
#define M_FILL 128  // [100] scatter fill counters
#define M_SEG 256   // [101] padded start column per class
#define M_TC 384    // [356] class of each 128-col tile
#define M_NT 768    // number of 128-col tiles
#define M_NCOL 769  // total padded columns

// ws byte offsets
#define OFF_X2 4096
#define OFF_DB2 16384
#define OFF_MIN 262144
#define OFF_XB (1u << 21)
#define OFF_DBS (1u << 22)

__device__ __forceinline__ unsigned short f2bf(float f) {
  unsigned u = __float_as_uint(f);
  unsigned r = 0x7FFFu + ((u >> 16) & 1u);  // round-to-nearest-even
  return (unsigned short)((u + r) >> 16);
}

typedef const __attribute__((address_space(1))) void* gptr_t;
typedef __attribute__((address_space(3))) void* lptr_t;
__device__ __forceinline__ void gload_lds16(const void* g, void* l) {
  __builtin_amdgcn_global_load_lds((gptr_t)g, (lptr_t)l, 16, 0, 0);
}

// ---- class histogram (LDS-local then one flush per block) ----
__global__ void k_hist(const int* __restrict__ labels, int* __restrict__ meta) {
  __shared__ int h[CC];
  int t = threadIdx.x;
  if (t < CC) h[t] = 0;
  __syncthreads();
#pragma unroll
  for (int i = 0; i < 4; ++i) {
    int n = blockIdx.x * 1024 + i * 256 + t;
    atomicAdd(&h[labels[n]], 1);
  }
  __syncthreads();
  if (t < CC) atomicAdd(&meta[M_HIST + t], h[t]);
}

// ---- serial scan over 100 classes: segment starts, tile->class, NT ----
__global__ void k_scan(int* __restrict__ meta) {
  if (threadIdx.x == 0) {
    int col = 0, t = 0;
    for (int c = 0; c < CC; ++c) {
      meta[M_SEG + c] = col;
      int tiles = (meta[M_HIST + c] + 127) >> 7;
      for (int i = 0; i < tiles; ++i) meta[M_TC + t++] = c;
      col += tiles << 7;
    }
    meta[M_SEG + CC] = col;
    meta[M_NT] = t;
    meta[M_NCOL] = col;
  }
}

// ---- x: fp32 -> bf16 + row sumsq. One wave per row. ----
__global__ void k_prep_x(const float* __restrict__ x, unsigned short* __restrict__ xb,
                         float* __restrict__ x2) {
  int w = threadIdx.x >> 6, lane = threadIdx.x & 63;
  int q = blockIdx.x * 4 + w;
  const float4* row = (const float4*)(x + (size_t)q * DD);
  float4 v0 = row[lane * 2];
  float4 v1 = row[lane * 2 + 1];
  float s = v0.x * v0.x + v0.y * v0.y + v0.z * v0.z + v0.w * v0.w +
            v1.x * v1.x + v1.y * v1.y + v1.z * v1.z + v1.w * v1.w;
  u16x8 o;
  o[0] = f2bf(v0.x); o[1] = f2bf(v0.y); o[2] = f2bf(v0.z); o[3] = f2bf(v0.w);
  o[4] = f2bf(v1.x); o[5] = f2bf(v1.y); o[6] = f2bf(v1.z); o[7] = f2bf(v1.w);
  ((u16x8*)(xb + (size_t)q * DD))[lane] = o;
#pragma unroll
  for (int m = 32; m; m >>= 1) s += __shfl_xor(s, m);
  if (lane == 0) x2[q] = s;
}

// ---- db: scatter row n -> sorted padded position, fp32 -> bf16, sumsq ----
__global__ void k_scatter(const float* __restrict__ db, const int* __restrict__ labels,
                          int* __restrict__ meta, unsigned short* __restrict__ dbs,
                          float* __restrict__ db2s) {
  int w = threadIdx.x >> 6, lane = threadIdx.x & 63;
  int n = blockIdx.x * 4 + w;
  int c = labels[n];
  int pos = 0;
  if (lane == 0) pos = meta[M_SEG + c] + atomicAdd(&meta[M_FILL + c], 1);
  pos = __shfl(pos, 0);
  const float4* row = (const float4*)(db + (size_t)n * DD);
  float4 v0 = row[lane * 2];
  float4 v1 = row[lane * 2 + 1];
  float s = v0.x * v0.x + v0.y * v0.y + v0.z * v0.z + v0.w * v0.w +
            v1.x * v1.x + v1.y * v1.y + v1.z * v1.z + v1.w * v1.w;
  u16x8 o;
  o[0] = f2bf(v0.x); o[1] = f2bf(v0.y); o[2] = f2bf(v0.z); o[3] = f2bf(v0.w);
  o[4] = f2bf(v1.x); o[5] = f2bf(v1.y); o[6] = f2bf(v1.z); o[7] = f2bf(v1.w);
  ((u16x8*)(dbs + (size_t)pos * DD))[lane] = o;
#pragma unroll
  for (int m = 32; m; m >>= 1) s += __shfl_xor(s, m);
  if (lane == 0) db2s[pos] = s;
}

// ---- fill padded slots: zero rows, db2 = +inf (never wins the min) ----
__global__ void k_pad(const int* __restrict__ meta, unsigned short* __restrict__ dbs,
                      float* __restrict__ db2s) {
  int w = threadIdx.x >> 6, lane = threadIdx.x & 63;
  int p = blockIdx.x * 4 + w;
  if (p >= meta[M_NCOL]) return;
  int c = meta[M_TC + (p >> 7)];
  if (p - meta[M_SEG + c] < meta[M_HIST + c]) return;  // real row, written by scatter
  u16x8 z = {0, 0, 0, 0, 0, 0, 0, 0};
  ((u16x8*)(dbs + (size_t)p * DD))[lane] = z;
  if (lane == 0) db2s[p] = __builtin_inff();
}

__global__ void k_initmin(unsigned* __restrict__ mb) {
  int i = blockIdx.x * 256 + threadIdx.x;
  if (i < QN * CC) mb[i] = 0x7F800000u;  // +inf bits
}

// ---- fused bf16 MFMA GEMM (128x128 tile, BK=32) + per-class row-min ----
__launch_bounds__(256)
__global__ void k_gemm(const unsigned short* __restrict__ xb,
                       const unsigned short* __restrict__ dbs,
                       const float* __restrict__ x2, const float* __restrict__ db2s,
                       const int* __restrict__ meta, unsigned* __restrict__ minbits) {
  int tq = blockIdx.x, tn = blockIdx.y;
  if (tn >= meta[M_NT]) return;
  int cls = meta[M_TC + tn];

  __shared__ __align__(16) unsigned short As[128 * 32];
  __shared__ __align__(16) unsigned short Bs[128 * 32];

  int t = threadIdx.x;
  int lane = t & 63;
  int wid = t >> 6;
  int wm = wid >> 1, wn = wid & 1;  // 2x2 waves of 64x64

  f32x4 acc[4][4];
#pragma unroll
  for (int m = 0; m < 4; ++m)
#pragma unroll
    for (int n = 0; n < 4; ++n) acc[m][n] = (f32x4){0.f, 0.f, 0.f, 0.f};

  // staging: thread t loads 16B for row j*64 + t/4, col (t&3)*8 (x2 chunks j=0,1)
  const unsigned short* Abase = xb + (size_t)tq * 128 * DD + (size_t)(t >> 2) * DD + (t & 3) * 8;
  const unsigned short* Bbase = dbs + (size_t)tn * 128 * DD + (size_t)(t >> 2) * DD + (t & 3) * 8;

  for (int kt = 0; kt < DD / 32; ++kt) {
    int k0 = kt * 32;
#pragma unroll
    for (int j = 0; j < 2; ++j) {
      gload_lds16(Abase + (size_t)j * 64 * DD + k0, As + j * 2048 + t * 8);
      gload_lds16(Bbase + (size_t)j * 64 * DD + k0, Bs + j * 2048 + t * 8);
    }
    asm volatile("s_waitcnt vmcnt(0)" ::: "memory");
    __syncthreads();

    bf16x8 af[4], bfb[4];
#pragma unroll
    for (int m = 0; m < 4; ++m)
      af[m] = *(const bf16x8*)(As + (wm * 64 + m * 16 + (lane & 15)) * 32 + (lane >> 4) * 8);
#pragma unroll
    for (int n = 0; n < 4; ++n)
      bfb[n] = *(const bf16x8*)(Bs + (wn * 64 + n * 16 + (lane & 15)) * 32 + (lane >> 4) * 8);
#pragma unroll
    for (int m = 0; m < 4; ++m)
#pragma unroll
      for (int n = 0; n < 4; ++n)
        acc[m][n] = __builtin_amdgcn_mfma_f32_16x16x32_bf16(af[m], bfb[n], acc[m][n], 0, 0, 0);
    __syncthreads();
  }

  // Epilogue: whole block is one class. d2 = x2[q] + min_n(db2[n] - 2*dot).
  int g = lane >> 4;
  int cl = lane & 15;
  float db2v[4];
#pragma unroll
  for (int n = 0; n < 4; ++n) db2v[n] = db2s[tn * 128 + wn * 64 + n * 16 + cl];

#pragma unroll
  for (int m = 0; m < 4; ++m) {
    int rowb = tq * 128 + wm * 64 + m * 16 + g * 4;
#pragma unroll
    for (int r = 0; r < 4; ++r) {
      float v = db2v[0] - 2.0f * acc[m][0][r];
      v = fminf(v, db2v[1] - 2.0f * acc[m][1][r]);
      v = fminf(v, db2v[2] - 2.0f * acc[m][2][r]);
      v = fminf(v, db2v[3] - 2.0f * acc[m][3][r]);
#pragma unroll
      for (int s = 1; s < 16; s <<= 1) v = fminf(v, __shfl_xor(v, s));
      if (cl == 0) {
        float d = sqrtf(fmaxf(x2[rowb + r] + v, 0.0f));
        atomicMin(minbits + (size_t)(rowb + r) * CC + cls, __float_as_uint(d));
      }
    }
  }
}

__global__ void k_final(const unsigned* __restrict__ mb, float* __restrict__ out) {
  int i = blockIdx.x * 256 + threadIdx.x;
  if (i < QN * CC) out[i] = -__uint_as_float(mb[i]);
}

extern "C" void kernel_launch(void* const* d_in, const int* in_sizes, int n_in,
                              void* d_out, int out_size, void* d_ws, size_t ws_size,
                              hipStream_t stream) {
  (void)in_sizes; (void)n_in; (void)out_size; (void)ws_size;
  const float* x = (const float*)d_in[0];
  const float* db = (const float*)d_in[1];
  const int* labels = (const int*)d_in[2];

  char* ws = (char*)d_ws;
  int* meta = (int*)ws;
  float* x2 = (float*)(ws + OFF_X2);
  float* db2s = (float*)(ws + OFF_DB2);
  unsigned* minbits = (unsigned*)(ws + OFF_MIN);
  unsigned short* xb = (unsigned short*)(ws + OFF_XB);
  unsigned short* dbs = (unsigned short*)(ws + OFF_DBS);

  hipMemsetAsync(ws, 0, 4096, stream);
  k_hist<<<NN / 1024, 256, 0, stream>>>(labels, meta);
  k_scan<<<1, 64, 0, stream>>>(meta);
  k_prep_x<<<QN / 4, 256, 0, stream>>>(x, xb, x2);
  k_scatter<<<NN / 4, 256, 0, stream>>>(db, labels, meta, dbs, db2s);
  k_pad<<<MAXNP / 4, 256, 0, stream>>>(meta, dbs, db2s);
  k_initmin<<<(QN * CC + 255) / 256, 256, 0, stream>>>(minbits);
  k_gemm<<<dim3(16, MAXTILES), 256, 0, stream>>>(xb, dbs, x2, db2s, meta, minbits);
  k_final<<<(QN * CC + 255) / 256, 256, 0, stream>>>(minbits, (float*)d_out);
}